// Round 1
// baseline (4067.649 us; speedup 1.0000x reference)
//
#include <hip/hip_runtime.h>

typedef __attribute__((ext_vector_type(4))) float f32x4;
typedef __attribute__((ext_vector_type(8))) short short8;
typedef __attribute__((ext_vector_type(4))) short short4_t;

__device__ __forceinline__ short f2bf(float f) {
  unsigned u = __float_as_uint(f);
  u += 0x7fffu + ((u >> 16) & 1u);   // round-to-nearest-even
  return (short)(u >> 16);
}

__device__ __forceinline__ float tanh_fast(float x) {
  // tanh(x) = 1 - 2/(e^{2x}+1); handles +-inf correctly
  float e = __expf(2.0f * x);
  return 1.0f - __fdividef(2.0f, e + 1.0f);
}

// ---------------------------------------------------------------- convert W,U -> bf16
__global__ __launch_bounds__(256) void convert_wu(
    const float* __restrict__ W, const float* __restrict__ U,
    short* __restrict__ Wb, short* __restrict__ Ub) {
  int i = blockIdx.x * 256 + threadIdx.x;
  if (i < 65536) {                       // W: 262144 floats = 65536 float4
    f32x4 v = ((const f32x4*)W)[i];
    short4_t s;
    s.x = f2bf(v.x); s.y = f2bf(v.y); s.z = f2bf(v.z); s.w = f2bf(v.w);
    ((short4_t*)Wb)[i] = s;
  } else if (i < 98304) {                // U: 131072 floats = 32768 float4
    int k = i - 65536;
    f32x4 v = ((const f32x4*)U)[k];
    short4_t s;
    s.x = f2bf(v.x); s.y = f2bf(v.y); s.z = f2bf(v.z); s.w = f2bf(v.w);
    ((short4_t*)Ub)[k] = s;
  }
}

// ---------------------------------------------------------------- xu = x @ U^T  (bf16 MFMA)
// x: [65536, 256] fp32, Ub: [512, 256] bf16, out: [65536, 512] fp32
// grid: 512 m-tiles x 4 n-tiles, block 256 (4 waves, 2x2 of 64x64)
__global__ __launch_bounds__(256) void xu_gemm(
    const float* __restrict__ x, const short* __restrict__ Ub,
    float* __restrict__ out) {
  __shared__ __attribute__((aligned(16))) short a_lds[128][272];  // pad: 544B rows (16B mult)
  __shared__ __attribute__((aligned(16))) short b_lds[128][272];
  const int tid = threadIdx.x;
  const int mb = blockIdx.x >> 2;
  const int nb = blockIdx.x & 3;

  // stage A: 128 rows x 256 fp32 -> bf16 LDS
  const float* xb = x + (size_t)mb * (128 * 256);
  for (int c = 0; c < 32; ++c) {
    int idx = c * 256 + tid;            // 8192 float4 chunks, coalesced
    int r = idx >> 6, c4 = idx & 63;
    f32x4 v = ((const f32x4*)xb)[idx];
    short4_t s;
    s.x = f2bf(v.x); s.y = f2bf(v.y); s.z = f2bf(v.z); s.w = f2bf(v.w);
    *(short4_t*)&a_lds[r][c4 * 4] = s;
  }
  // stage B: U rows [nb*128, +128), already bf16
  const short* ub = Ub + nb * (128 * 256);
  for (int c = 0; c < 16; ++c) {
    int idx = c * 256 + tid;            // 4096 short8 chunks
    int r = idx >> 5, ch = idx & 31;
    *(short8*)&b_lds[r][ch * 8] = ((const short8*)ub)[idx];
  }
  __syncthreads();

  const int lane = tid & 63, wave = tid >> 6;
  const int wr = wave >> 1, wc = wave & 1;     // 2x2 wave grid of 64x64
  const int lr = lane & 15, lk = lane >> 4;
  const f32x4 zero = {0.f, 0.f, 0.f, 0.f};
  f32x4 acc[4][4];
  #pragma unroll
  for (int mt = 0; mt < 4; ++mt)
    #pragma unroll
    for (int nt = 0; nt < 4; ++nt) acc[mt][nt] = zero;

  #pragma unroll
  for (int kt = 0; kt < 8; ++kt) {
    const int k = kt * 32 + lk * 8;
    short8 a[4], b[4];
    #pragma unroll
    for (int mt = 0; mt < 4; ++mt)
      a[mt] = *(const short8*)&a_lds[wr * 64 + mt * 16 + lr][k];
    #pragma unroll
    for (int nt = 0; nt < 4; ++nt)
      b[nt] = *(const short8*)&b_lds[wc * 64 + nt * 16 + lr][k];
    #pragma unroll
    for (int mt = 0; mt < 4; ++mt)
      #pragma unroll
      for (int nt = 0; nt < 4; ++nt)
        acc[mt][nt] = __builtin_amdgcn_mfma_f32_16x16x32_bf16(a[mt], b[nt], acc[mt][nt], 0, 0, 0);
  }

  #pragma unroll
  for (int mt = 0; mt < 4; ++mt)
    #pragma unroll
    for (int nt = 0; nt < 4; ++nt)
      #pragma unroll
      for (int q = 0; q < 4; ++q) {
        int row = mb * 128 + wr * 64 + mt * 16 + lk * 4 + q;
        int col = nb * 128 + wc * 64 + nt * 16 + lr;
        out[(size_t)row * 512 + col] = acc[mt][nt][q];
      }
}

// ---------------------------------------------------------------- recurrence scan
// 4 blocks x 512 threads (8 waves). Block owns 16 batch rows for all 1024 steps.
// W bf16 resident: k in [0,384) in registers (MFMA B-frag layout, 192 VGPR),
// k in [384,512) in LDS. h kept in registers in C-fragment layout.
// out holds xu on entry (read), overwritten with h in place.
__global__ __launch_bounds__(512, 2) void rnn_scan(
    const short* __restrict__ Wb, float* __restrict__ out) {
  __shared__ __attribute__((aligned(16))) short w_lds[512][136];  // k 384..512, 272B rows
  __shared__ __attribute__((aligned(16))) short a_lds[16][520];   // tanh(h) bf16, 1040B rows
  const int tid = threadIdx.x;
  const int blk = blockIdx.x;             // 0..3 -> batch rows 16*blk..
  const int lane = tid & 63, wave = tid >> 6;
  const int j0 = wave * 64;               // wave's 64-wide output slice
  const int lr = lane & 15, lk = lane >> 4;

  // register-resident W fragments: B[k][j] = W[j][k], lane holds 8 contiguous k
  short8 wreg[4][12];
  #pragma unroll
  for (int jt = 0; jt < 4; ++jt) {
    const short* wrow = Wb + (j0 + jt * 16 + lr) * 512 + lk * 8;
    #pragma unroll
    for (int kt = 0; kt < 12; ++kt)
      wreg[jt][kt] = *(const short8*)(wrow + kt * 32);
  }
  // stage LDS-resident W slice (k in [384,512)): 512 rows x 16 short8-chunks
  for (int c = 0; c < 16; ++c) {
    int idx = c * 512 + tid;
    int j = idx >> 4, ch = idx & 15;
    *(short8*)&w_lds[j][ch * 8] = *(const short8*)(Wb + j * 512 + 384 + ch * 8);
  }

  float h[4][4];                          // [jt][q]: row = lk*4+q, col = j0+jt*16+lr
  #pragma unroll
  for (int jt = 0; jt < 4; ++jt)
    #pragma unroll
    for (int q = 0; q < 4; ++q) h[jt][q] = 0.f;

  const int base = (blk * 16 + lk * 4) * 524288 + j0 + lr;  // ((row)*1024 + 0)*512 + col
  __syncthreads();

  for (int t = 0; t < 1024; ++t) {
    // issue xu loads early (hidden under tanh + MFMA)
    float xu[4][4];
    #pragma unroll
    for (int q = 0; q < 4; ++q)
      #pragma unroll
      for (int jt = 0; jt < 4; ++jt)
        xu[jt][q] = out[base + q * 524288 + t * 512 + jt * 16];

    // A = tanh(h) -> bf16 staging
    #pragma unroll
    for (int jt = 0; jt < 4; ++jt)
      #pragma unroll
      for (int q = 0; q < 4; ++q)
        a_lds[lk * 4 + q][j0 + jt * 16 + lr] = f2bf(tanh_fast(h[jt][q]));
    __syncthreads();

    f32x4 acc[4];
    const f32x4 zero = {0.f, 0.f, 0.f, 0.f};
    #pragma unroll
    for (int jt = 0; jt < 4; ++jt) acc[jt] = zero;

    #pragma unroll
    for (int kt = 0; kt < 16; ++kt) {
      short8 a = *(const short8*)&a_lds[lr][kt * 32 + lk * 8];
      if (kt < 12) {
        #pragma unroll
        for (int jt = 0; jt < 4; ++jt)
          acc[jt] = __builtin_amdgcn_mfma_f32_16x16x32_bf16(a, wreg[jt][kt], acc[jt], 0, 0, 0);
      } else {
        #pragma unroll
        for (int jt = 0; jt < 4; ++jt) {
          short8 b = *(const short8*)&w_lds[j0 + jt * 16 + lr][(kt - 12) * 32 + lk * 8];
          acc[jt] = __builtin_amdgcn_mfma_f32_16x16x32_bf16(a, b, acc[jt], 0, 0, 0);
        }
      }
    }

    // h' = h + alpha*(acc + xu - h); store to out (in place over xu[t])
    #pragma unroll
    for (int jt = 0; jt < 4; ++jt)
      #pragma unroll
      for (int q = 0; q < 4; ++q) {
        float v = h[jt][q];
        v = v + 0.1f * (acc[jt][q] + xu[jt][q] - v);
        h[jt][q] = v;
        out[base + q * 524288 + t * 512 + jt * 16] = v;
      }
    __syncthreads();   // a_lds reads done before next iteration's writes
  }
}

// ----------------------------------------------------------------
extern "C" void kernel_launch(void* const* d_in, const int* in_sizes, int n_in,
                              void* d_out, int out_size, void* d_ws, size_t ws_size,
                              hipStream_t stream) {
  (void)in_sizes; (void)n_in; (void)out_size; (void)ws_size;
  const float* x = (const float*)d_in[0];   // [64,1024,256]
  const float* W = (const float*)d_in[1];   // [512,512]
  const float* U = (const float*)d_in[2];   // [512,256]
  float* out = (float*)d_out;               // [64,1024,512]
  short* Wb = (short*)d_ws;                 // 512*512 bf16 = 512KB
  short* Ub = Wb + 512 * 512;               // 512*256 bf16 = 256KB

  convert_wu<<<384, 256, 0, stream>>>(W, U, Wb, Ub);
  xu_gemm<<<2048, 256, 0, stream>>>(x, Ub, out);
  rnn_scan<<<4, 512, 0, stream>>>(Wb, out);
}

// Round 2
// 3179.412 us; speedup vs baseline: 1.2794x; 1.2794x over previous
//
#include <hip/hip_runtime.h>

typedef __attribute__((ext_vector_type(4))) float f32x4;
typedef __attribute__((ext_vector_type(8))) short short8;
typedef __attribute__((ext_vector_type(4))) short short4_t;

__device__ __forceinline__ short f2bf(float f) {
  unsigned u = __float_as_uint(f);
  u += 0x7fffu + ((u >> 16) & 1u);   // round-to-nearest-even
  return (short)(u >> 16);
}

__device__ __forceinline__ float tanh_fast(float x) {
  float e = __expf(2.0f * x);
  return 1.0f - __fdividef(2.0f, e + 1.0f);
}

// ---------------------------------------------------------------- convert W,U -> bf16
__global__ __launch_bounds__(256) void convert_wu(
    const float* __restrict__ W, const float* __restrict__ U,
    short* __restrict__ Wb, short* __restrict__ Ub) {
  int i = blockIdx.x * 256 + threadIdx.x;
  if (i < 65536) {
    f32x4 v = ((const f32x4*)W)[i];
    short4_t s;
    s.x = f2bf(v.x); s.y = f2bf(v.y); s.z = f2bf(v.z); s.w = f2bf(v.w);
    ((short4_t*)Wb)[i] = s;
  } else if (i < 98304) {
    int k = i - 65536;
    f32x4 v = ((const f32x4*)U)[k];
    short4_t s;
    s.x = f2bf(v.x); s.y = f2bf(v.y); s.z = f2bf(v.z); s.w = f2bf(v.w);
    ((short4_t*)Ub)[k] = s;
  }
}

// ---------------------------------------------------------------- xu = x @ U^T  (bf16 MFMA)
__global__ __launch_bounds__(256) void xu_gemm(
    const float* __restrict__ x, const short* __restrict__ Ub,
    float* __restrict__ out) {
  __shared__ __attribute__((aligned(16))) short a_lds[128][272];
  __shared__ __attribute__((aligned(16))) short b_lds[128][272];
  const int tid = threadIdx.x;
  const int mb = blockIdx.x >> 2;
  const int nb = blockIdx.x & 3;

  const float* xb = x + (size_t)mb * (128 * 256);
  for (int c = 0; c < 32; ++c) {
    int idx = c * 256 + tid;
    int r = idx >> 6, c4 = idx & 63;
    f32x4 v = ((const f32x4*)xb)[idx];
    short4_t s;
    s.x = f2bf(v.x); s.y = f2bf(v.y); s.z = f2bf(v.z); s.w = f2bf(v.w);
    *(short4_t*)&a_lds[r][c4 * 4] = s;
  }
  const short* ub = Ub + nb * (128 * 256);
  for (int c = 0; c < 16; ++c) {
    int idx = c * 256 + tid;
    int r = idx >> 5, ch = idx & 31;
    *(short8*)&b_lds[r][ch * 8] = ((const short8*)ub)[idx];
  }
  __syncthreads();

  const int lane = tid & 63, wave = tid >> 6;
  const int wr = wave >> 1, wc = wave & 1;
  const int lr = lane & 15, lk = lane >> 4;
  const f32x4 zero = {0.f, 0.f, 0.f, 0.f};
  f32x4 acc[4][4];
  #pragma unroll
  for (int mt = 0; mt < 4; ++mt)
    #pragma unroll
    for (int nt = 0; nt < 4; ++nt) acc[mt][nt] = zero;

  #pragma unroll
  for (int kt = 0; kt < 8; ++kt) {
    const int k = kt * 32 + lk * 8;
    short8 a[4], b[4];
    #pragma unroll
    for (int mt = 0; mt < 4; ++mt)
      a[mt] = *(const short8*)&a_lds[wr * 64 + mt * 16 + lr][k];
    #pragma unroll
    for (int nt = 0; nt < 4; ++nt)
      b[nt] = *(const short8*)&b_lds[wc * 64 + nt * 16 + lr][k];
    #pragma unroll
    for (int mt = 0; mt < 4; ++mt)
      #pragma unroll
      for (int nt = 0; nt < 4; ++nt)
        acc[mt][nt] = __builtin_amdgcn_mfma_f32_16x16x32_bf16(a[mt], b[nt], acc[mt][nt], 0, 0, 0);
  }

  #pragma unroll
  for (int mt = 0; mt < 4; ++mt)
    #pragma unroll
    for (int nt = 0; nt < 4; ++nt)
      #pragma unroll
      for (int q = 0; q < 4; ++q) {
        int row = mb * 128 + wr * 64 + mt * 16 + lk * 4 + q;
        int col = nb * 128 + wc * 64 + nt * 16 + lr;
        out[(size_t)row * 512 + col] = acc[mt][nt][q];
      }
}

// ---------------------------------------------------------------- recurrence scan
// 4 blocks x 512 threads (8 waves, 2/SIMD, 1 block/CU). Block owns 16 batch rows.
// W bf16: k in [0,384) pinned in registers (192 VGPR, asm-kept), k in [384,512) in LDS.
// xu folded into MFMA C-operand; xu loads rotated to previous iteration's tail.
__global__ __launch_bounds__(512, 2) void rnn_scan(
    const short* __restrict__ Wb, float* __restrict__ out) {
  __shared__ __attribute__((aligned(16))) short w_lds[512][136];  // k 384..512
  __shared__ __attribute__((aligned(16))) short a_lds[16][520];   // tanh(h) bf16
  const int tid = threadIdx.x;
  const int blk = blockIdx.x;
  const int lane = tid & 63, wave = tid >> 6;
  const int j0 = wave * 64;
  const int lr = lane & 15, lk = lane >> 4;

  // register-resident W fragments: B[k][j] = W[j][k]
  short8 wreg[4][12];
  #pragma unroll
  for (int jt = 0; jt < 4; ++jt) {
    const short* wrow = Wb + (j0 + jt * 16 + lr) * 512 + lk * 8;
    #pragma unroll
    for (int kt = 0; kt < 12; ++kt)
      wreg[jt][kt] = *(const short8*)(wrow + kt * 32);
  }
  // pin: make each fragment an opaque asm result so the compiler cannot
  // sink/rematerialize the loads into the loop (R1: it did, -> 3.9us/step)
  #pragma unroll
  for (int jt = 0; jt < 4; ++jt)
    #pragma unroll
    for (int kt = 0; kt < 12; ++kt)
      asm volatile("" : "+v"(wreg[jt][kt]));

  // LDS-resident W slice (k in [384,512))
  for (int c = 0; c < 16; ++c) {
    int idx = c * 512 + tid;
    int j = idx >> 4, ch = idx & 15;
    *(short8*)&w_lds[j][ch * 8] = *(const short8*)(Wb + j * 512 + 384 + ch * 8);
  }

  float h[4][4];
  #pragma unroll
  for (int jt = 0; jt < 4; ++jt)
    #pragma unroll
    for (int q = 0; q < 4; ++q) h[jt][q] = 0.f;

  const size_t base = (size_t)(blk * 16 + lk * 4) * 524288 + j0 + lr;
  __syncthreads();

  f32x4 acc[4];
  // prologue: acc <- xu[t=0]
  {
    const float* p = out + base;
    #pragma unroll
    for (int jt = 0; jt < 4; ++jt)
      #pragma unroll
      for (int q = 0; q < 4; ++q)
        acc[jt][q] = p[(size_t)q * 524288 + jt * 16];
  }

  for (int t = 0; t < 1024; ++t) {
    // A = tanh(h) -> bf16 staging
    #pragma unroll
    for (int jt = 0; jt < 4; ++jt)
      #pragma unroll
      for (int q = 0; q < 4; ++q)
        a_lds[lk * 4 + q][j0 + jt * 16 + lr] = f2bf(tanh_fast(h[jt][q]));
    __syncthreads();

    // acc (holds xu_t) += tanh(h) @ W^T
    #pragma unroll
    for (int kt = 0; kt < 16; ++kt) {
      short8 a = *(const short8*)&a_lds[lr][kt * 32 + lk * 8];
      if (kt < 12) {
        #pragma unroll
        for (int jt = 0; jt < 4; ++jt)
          acc[jt] = __builtin_amdgcn_mfma_f32_16x16x32_bf16(a, wreg[jt][kt], acc[jt], 0, 0, 0);
      } else {
        #pragma unroll
        for (int jt = 0; jt < 4; ++jt) {
          short8 b = *(const short8*)&w_lds[j0 + jt * 16 + lr][(kt - 12) * 32 + lk * 8];
          acc[jt] = __builtin_amdgcn_mfma_f32_16x16x32_bf16(a, b, acc[jt], 0, 0, 0);
        }
      }
    }

    // h' = 0.9*h + 0.1*acc; store in place over xu[t]
    float* po = out + base + (size_t)t * 512;
    #pragma unroll
    for (int jt = 0; jt < 4; ++jt)
      #pragma unroll
      for (int q = 0; q < 4; ++q) {
        float v = 0.9f * h[jt][q] + 0.1f * acc[jt][q];
        h[jt][q] = v;
        po[(size_t)q * 524288 + jt * 16] = v;
      }
    __syncthreads();  // a_lds reads done before next iteration's writes

    // tail: prefetch next step's xu into acc (hides L3 latency under
    // loop-back + tanh + staging + barrier)
    int tn = t + 1; if (tn > 1023) tn = 1023;
    const float* pn = out + base + (size_t)tn * 512;
    #pragma unroll
    for (int jt = 0; jt < 4; ++jt)
      #pragma unroll
      for (int q = 0; q < 4; ++q)
        acc[jt][q] = pn[(size_t)q * 524288 + jt * 16];
  }
}

// ----------------------------------------------------------------
extern "C" void kernel_launch(void* const* d_in, const int* in_sizes, int n_in,
                              void* d_out, int out_size, void* d_ws, size_t ws_size,
                              hipStream_t stream) {
  (void)in_sizes; (void)n_in; (void)out_size; (void)ws_size;
  const float* x = (const float*)d_in[0];
  const float* W = (const float*)d_in[1];
  const float* U = (const float*)d_in[2];
  float* out = (float*)d_out;
  short* Wb = (short*)d_ws;
  short* Ub = Wb + 512 * 512;

  convert_wu<<<384, 256, 0, stream>>>(W, U, Wb, Ub);
  xu_gemm<<<2048, 256, 0, stream>>>(x, Ub, out);
  rnn_scan<<<4, 512, 0, stream>>>(Wb, out);
}